// Round 1
// baseline (96.778 us; speedup 1.0000x reference)
//
#include <hip/hip_runtime.h>
#include <math.h>

#define NHEADS 16
#define HD 64
#define DMODEL 1024          // NHEADS * HD
#define QK_PAD 68            // row stride in floats (64 + 4 pad) -> 2-way banks, free

__global__ __launch_bounds__(256) void temporal_attn_kernel(
    const float* __restrict__ q,
    const float* __restrict__ k,
    const float* __restrict__ v,
    float* __restrict__ out)
{
    __shared__ float  qs[NHEADS * QK_PAD];
    __shared__ float  ks[NHEADS * QK_PAD];
    __shared__ float4 vs[NHEADS * (HD / 4)];   // unpadded: b128 reads are 2-way (free)
    __shared__ float  ps[NHEADS][NHEADS + 1];

    const int t = threadIdx.x;
    const size_t base = (size_t)blockIdx.x * DMODEL;
    const int r = t >> 4;   // row   0..15
    const int c = t & 15;   // col/4 0..15

    // ---- stage token tiles: fully coalesced, 16B/lane ----
    const float4 qv = ((const float4*)(q + base))[t];
    const float4 kv = ((const float4*)(k + base))[t];
    const float4 vv = ((const float4*)(v + base))[t];
    *((float4*)&qs[r * QK_PAD + 4 * c]) = qv;
    *((float4*)&ks[r * QK_PAD + 4 * c]) = kv;
    vs[t] = vv;
    __syncthreads();

    // ---- scores: thread t owns s[i=r][j=c] = (q_row_r . k_row_c) / 8 ----
    const float4* qi = (const float4*)&qs[r * QK_PAD];
    const float4* kj = (const float4*)&ks[c * QK_PAD];
    float acc = 0.f;
    #pragma unroll
    for (int d = 0; d < HD / 4; ++d) {
        const float4 a = qi[d];
        const float4 b = kj[d];
        acc = fmaf(a.x, b.x, acc);
        acc = fmaf(a.y, b.y, acc);
        acc = fmaf(a.z, b.z, acc);
        acc = fmaf(a.w, b.w, acc);
    }
    acc *= 0.125f;                 // 1/sqrt(64)
    if (c > r) acc = -1e30f;       // causal over heads

    // ---- softmax over j within each 16-lane row group ----
    float m = acc;
    #pragma unroll
    for (int mask = 8; mask >= 1; mask >>= 1)
        m = fmaxf(m, __shfl_xor(m, mask, 16));
    const float p = __expf(acc - m);   // masked lanes: exp(-huge) == 0
    float s = p;
    #pragma unroll
    for (int mask = 8; mask >= 1; mask >>= 1)
        s += __shfl_xor(s, mask, 16);
    ps[r][c] = p / s;
    __syncthreads();

    // ---- PV: out[i=r][4c..4c+3] = sum_j p[i][j] * v[j][4c..4c+3] ----
    float4 o = make_float4(0.f, 0.f, 0.f, 0.f);
    #pragma unroll
    for (int j = 0; j < NHEADS; ++j) {
        const float  pij = ps[r][j];
        const float4 vj  = vs[j * (HD / 4) + c];
        o.x = fmaf(pij, vj.x, o.x);
        o.y = fmaf(pij, vj.y, o.y);
        o.z = fmaf(pij, vj.z, o.z);
        o.w = fmaf(pij, vj.w, o.w);
    }
    ((float4*)(out + base))[t] = o;
}

extern "C" void kernel_launch(void* const* d_in, const int* in_sizes, int n_in,
                              void* d_out, int out_size, void* d_ws, size_t ws_size,
                              hipStream_t stream) {
    const float* q = (const float*)d_in[0];
    const float* k = (const float*)d_in[1];
    const float* v = (const float*)d_in[2];
    float* o = (float*)d_out;
    const int ntok = in_sizes[0] / DMODEL;   // B*S tokens, one block each
    temporal_attn_kernel<<<ntok, 256, 0, stream>>>(q, k, v, o);
}